// Round 7
// baseline (1177.866 us; speedup 1.0000x reference)
//
#include <hip/hip_runtime.h>
#include <math.h>

#define NB 512
#define NL 336
#define NC 321
#define NS 28
#define NW 12
#define NH 25
#define NP 8
#define NG 100
#define NT (NS + NP - 1)  // 35 cell steps
#define BSL 16            // batch slab per wave
#define RSTF 36           // h-row stride in f32 slots
#define WPB 4             // waves per block

typedef __attribute__((ext_vector_type(8))) short bf16x8;
typedef __attribute__((ext_vector_type(4))) float f32x4;

union B8 { bf16x8 v; short s[8]; };
union BU { bf16x8 v; unsigned u[4]; };

// round-to-nearest bf16 (weights, built once)
__device__ __forceinline__ short brtn_s(float x) {
    union { float f; unsigned u; } c; c.f = x;
    return (short)((c.u + 0x8000u) >> 16);
}
__device__ __forceinline__ float fhi_f(float x) {
    union { float f; unsigned u; } c; c.f = x; c.u &= 0xFFFF0000u; return c.f;
}
__device__ __forceinline__ short bhi_s(float x) {
    union { float f; unsigned u; } c; c.f = x; return (short)(c.u >> 16);
}
__device__ __forceinline__ unsigned pack_hi2(float a, float b) {
    union { float f; unsigned u; } x, y; x.f = a; y.f = b;
    return (x.u >> 16) | (y.u & 0xFFFF0000u);
}
__device__ __forceinline__ float sigtanh(float a, float b) {
    float ea = __expf(-a);
    float eb = __expf(-2.0f * b);
    return __fdividef(1.0f - eb, (1.0f + ea) * (1.0f + eb));
}
__device__ __forceinline__ float sigm_f(float x) {
    return __fdividef(1.0f, 1.0f + __expf(-x));
}

// build hi/lo bf16 B-fragments from two f32x4 h-rows (+ q3 slot overrides)
__device__ __forceinline__ void pack_frag(const f32x4& r0, const f32x4& r1,
                                          bool q3, BU& ph, BU& pl) {
    ph.u[0] = pack_hi2(r0[0], r0[1]);
    ph.u[1] = pack_hi2(r0[2], r0[3]);
    ph.u[2] = pack_hi2(r1[0], r1[1]);
    ph.u[3] = pack_hi2(r1[2], r1[3]);
    const float d0 = r0[0] - fhi_f(r0[0]);
    const float d1 = r0[1] - fhi_f(r0[1]);
    const float d2 = r0[2] - fhi_f(r0[2]);
    const float d3 = r0[3] - fhi_f(r0[3]);
    const float d4 = r1[0] - fhi_f(r1[0]);
    const float d5 = r1[1] - fhi_f(r1[1]);
    const float d6 = r1[2] - fhi_f(r1[2]);
    const float d7 = r1[3] - fhi_f(r1[3]);
    pl.u[0] = pack_hi2(d0, d1);
    pl.u[1] = pack_hi2(d2, d3);
    pl.u[2] = pack_hi2(d4, d5);
    pl.u[3] = pack_hi2(d6, d7);
    // q==3: k26 -> 1@hi (bias_hi), k27 -> 1@lo (bias_lo), k28 -> xt_hi (wx_lo)
    union { float f; unsigned u; } xu; xu.f = r0[1];  // hf[25] = xt when q==3
    ph.u[1] = q3 ? 0x00003F80u : ph.u[1];
    pl.u[1] = q3 ? 0x3F800000u : pl.u[1];
    ph.u[2] = q3 ? (xu.u >> 16) : ph.u[2];
    pl.u[2] = q3 ? 0u : pl.u[2];
}

// ---------------- Stage 1: mean + segment embedding (transposed out) --------
extern "C" __global__ __launch_bounds__(384)
void k_seg(const float* __restrict__ x, const float* __restrict__ seg,
           float* __restrict__ seg_inT, float* __restrict__ meanw) {
    const int b = blockIdx.x;
    const int c = threadIdx.x;
    if (c >= NC) return;
    float sw[NW];
#pragma unroll
    for (int w = 0; w < NW; ++w) sw[w] = seg[c * NW + w];
    float acc[NS];
    float sum = 0.0f;
    const float* xb = x + (size_t)b * NL * NC + c;
#pragma unroll 1
    for (int s = 0; s < NS; ++s) {
        float a = 0.0f;
#pragma unroll
        for (int w = 0; w < NW; ++w) {
            float v = xb[(s * NW + w) * NC];
            sum += v;
            a = fmaf(v, sw[w], a);
        }
        acc[s] = a;
    }
    const float mean = sum * (1.0f / (float)NL);
    float ssum = 0.0f;
#pragma unroll
    for (int w = 0; w < NW; ++w) ssum += sw[w];
    meanw[b * NC + c] = mean;
#pragma unroll
    for (int s = 0; s < NS; ++s)
        seg_inT[((size_t)s * NC + c) * NB + b] = acc[s] - mean * ssum;
}

// ---------------- Stage 2: MFMA LSTM (template: V=0 real, V=1..3 probes) ----
// V0: full.  V1: activations -> fma-only (no trans).  V2: frozen B-fragments
// (ds_read kept+sunk, pack elided).  V3: h LDS-writes elided (hn sunk).
template<int V>
__global__ __launch_bounds__(256, 4)
void k_lstm_t(const float* __restrict__ seg_inT, const float* __restrict__ W_ih,
              const float* __restrict__ W_hh, const float* __restrict__ b_ih,
              const float* __restrict__ b_hh, const float* __restrict__ Wp,
              const float* __restrict__ bp, float* __restrict__ preds) {
    const int c = blockIdx.x;
    const int wv = threadIdx.x >> 6;
    const int lane = threadIdx.x & 63;
    const int b0 = (blockIdx.y * WPB + wv) * BSL;
    const int bb = lane & 15;
    const int q  = lane >> 4;

    __shared__ __align__(16) float hbuf[WPB][BSL * RSTF];
    float* __restrict__ hf = hbuf[wv];

    for (int i = lane; i < BSL * RSTF; i += 64) hf[i] = 0.0f;
    if (lane < BSL)
        hf[lane * RSTF + 25] = seg_inT[(size_t)c * NB + b0 + lane];  // s=0

    // ---- hoisted A-fragments from global (one-time, L2-resident) ----
    const int qq = bb >> 2, rr = bb & 3;
    const float* __restrict__ whh = W_hh + (size_t)c * NG * NH;
    const float* __restrict__ wxp = W_ih + (size_t)c * NG;
    const float* __restrict__ bip = b_ih + (size_t)c * NG;
    const float* __restrict__ bhp = b_hh + (size_t)c * NG;
    bf16x8 afr[7];
#pragma unroll 1
    for (int mg = 0; mg < 7; ++mg) {
        const int jj = qq * 7 + mg;
        const int grow = rr * NH + jj;
        B8 f0;
#pragma unroll
        for (int e = 0; e < 8; ++e) {
            const int k = q * 8 + e;
            short v0 = 0;
            if (jj < NH) {
                if (k < NH)         v0 = brtn_s(whh[grow * NH + k]);
                else if (k == 25)   v0 = brtn_s(wxp[grow]);
                else if (k == 26)   v0 = bhi_s(bip[grow] + bhp[grow]);
                else if (k == 27)   { const float bs = bip[grow] + bhp[grow];
                                      v0 = brtn_s(bs - fhi_f(bs)); }
                else if (k == 28)   { const float wx = wxp[grow];
                                      v0 = brtn_s(wx - fhi_f(wx)); }
            }
            f0.s[e] = v0;
        }
        afr[mg] = f0.v;
    }

    float wpl[7];
#pragma unroll
    for (int mg = 0; mg < 7; ++mg) {
        const int j = q * 7 + mg;
        wpl[mg] = (j < NH) ? Wp[(size_t)c * NH + j] : 0.0f;
    }
    const float bpc = bp[c];
    const bool q3 = (q == 3);

    // V2: freeze fragments built from the initial h state
    BU phF, plF;
    if constexpr (V == 2) {
        const f32x4 r0 = *(const f32x4*)&hf[bb * RSTF + q * 8];
        const f32x4 r1 = *(const f32x4*)&hf[bb * RSTF + q * 8 + 4];
        pack_frag(r0, r1, q3, phF, plF);
    }

    float cst[7];
#pragma unroll
    for (int mg = 0; mg < 7; ++mg) cst[mg] = 0.0f;

#pragma unroll 1
    for (int t = 0; t < NT; ++t) {
        const bool have_next = (t + 1 < NT);
        const bool enc_next = (t + 1 < NS);
        const bool do_proj = (t >= NS - 1);

        float xnext = 0.0f;
        if (enc_next && q == 0)
            xnext = seg_inT[((size_t)(t + 1) * NC + c) * NB + b0 + bb];

        const f32x4 r0 = *(const f32x4*)&hf[bb * RSTF + q * 8];
        const f32x4 r1 = *(const f32x4*)&hf[bb * RSTF + q * 8 + 4];
        BU ph, pl;
        if constexpr (V == 2) {
            asm volatile("" :: "v"(r0[0]), "v"(r0[1]), "v"(r0[2]), "v"(r0[3]),
                              "v"(r1[0]), "v"(r1[1]), "v"(r1[2]), "v"(r1[3]));
            ph = phF; pl = plF;
        } else {
            pack_frag(r0, r1, q3, ph, pl);
        }

        float pp = 0.0f;
#pragma unroll
        for (int mg = 0; mg < 7; ++mg) {
            f32x4 acc = {0.0f, 0.0f, 0.0f, 0.0f};
            acc = __builtin_amdgcn_mfma_f32_16x16x32_bf16(afr[mg], ph.v, acc, 0, 0, 0);
            acc = __builtin_amdgcn_mfma_f32_16x16x32_bf16(afr[mg], pl.v, acc, 0, 0, 0);
            float cn, hn;
            if constexpr (V == 1) {
                // same dep structure, no transcendentals
                cn = fmaf(acc[1] * 0.25f, cst[mg], acc[0] * acc[2] * 0.0625f);
                hn = fminf(fmaxf(acc[3] * cn * 0.25f, -1.0f), 1.0f);
            } else {
                cn = fmaf(sigm_f(acc[1]), cst[mg], sigtanh(acc[0], acc[2]));
                hn = sigtanh(acc[3], cn);
            }
            cst[mg] = cn;
            if (do_proj) pp = fmaf(hn, wpl[mg], pp);
            const int j = q * 7 + mg;
            if constexpr (V == 3) {
                asm volatile("" :: "v"(hn));
            } else {
                if (j < NH) hf[bb * RSTF + j] = hn;
            }
        }

        if (do_proj) {
            pp += __shfl_xor(pp, 16);
            pp += __shfl_xor(pp, 32);
            const float ov = pp + bpc;
            if (q == 0) {
                preds[((size_t)c * NP + (t - (NS - 1))) * NB + b0 + bb] = ov;
                if (have_next && !enc_next) hf[bb * RSTF + 25] = ov;
            }
        }
        if (enc_next && q == 0) hf[bb * RSTF + 25] = xnext;
    }
}

// ---------------- Stage 3: expand predictions to output ---------------------
extern "C" __global__ __launch_bounds__(384)
void k_out(const float* __restrict__ preds, const float* __restrict__ seg,
           const float* __restrict__ meanw, float* __restrict__ out) {
    const int b = blockIdx.x;
    const int c = threadIdx.x;
    if (c >= NC) return;
    float sw[NW];
#pragma unroll
    for (int w = 0; w < NW; ++w) sw[w] = seg[c * NW + w];
    const float mean = meanw[b * NC + c];
    float pv[NP];
#pragma unroll
    for (int p = 0; p < NP; ++p) pv[p] = preds[((size_t)c * NP + p) * NB + b];
    float* ob = out + (size_t)b * (NP * NW) * NC + c;
#pragma unroll
    for (int p = 0; p < NP; ++p) {
#pragma unroll
        for (int w = 0; w < NW; ++w) {
            ob[(p * NW + w) * NC] = fmaf(pv[p], sw[w], mean);
        }
    }
}

extern "C" void kernel_launch(void* const* d_in, const int* in_sizes, int n_in,
                              void* d_out, int out_size, void* d_ws, size_t ws_size,
                              hipStream_t stream) {
    const float* x    = (const float*)d_in[0];
    const float* seg  = (const float*)d_in[1];
    const float* W_ih = (const float*)d_in[2];
    const float* W_hh = (const float*)d_in[3];
    const float* b_ih = (const float*)d_in[4];
    const float* b_hh = (const float*)d_in[5];
    const float* Wp   = (const float*)d_in[6];
    const float* bp   = (const float*)d_in[7];
    float* out = (float*)d_out;

    float* seg_inT = (float*)d_ws;                     // 28*321*512
    float* meanw   = seg_inT + (size_t)NS * NC * NB;   // 512*321
    float* preds   = meanw + (size_t)NB * NC;          // 321*8*512

    k_seg<<<NB, 384, 0, stream>>>(x, seg, seg_inT, meanw);
    k_lstm_t<0><<<dim3(NC, NB / (BSL * WPB)), 256, 0, stream>>>(
        seg_inT, W_ih, W_hh, b_ih, b_hh, Wp, bp, preds);
    k_out<<<NB, 384, 0, stream>>>(preds, seg, meanw, out);

    // ---- ablation probes (half grid, scratch output; do not affect d_out) ----
    const size_t used = (size_t)NS * NC * NB + (size_t)NB * NC + (size_t)NC * NP * NB;
    const size_t need = (used + (size_t)NC * NP * NB) * sizeof(float);
    if (ws_size >= need) {
        float* pprobe = preds + (size_t)NC * NP * NB;
        dim3 g(NC, NB / (BSL * WPB) / 2);
        k_lstm_t<0><<<g, 256, 0, stream>>>(seg_inT, W_ih, W_hh, b_ih, b_hh, Wp, bp, pprobe);
        k_lstm_t<1><<<g, 256, 0, stream>>>(seg_inT, W_ih, W_hh, b_ih, b_hh, Wp, bp, pprobe);
        k_lstm_t<2><<<g, 256, 0, stream>>>(seg_inT, W_ih, W_hh, b_ih, b_hh, Wp, bp, pprobe);
        k_lstm_t<3><<<g, 256, 0, stream>>>(seg_inT, W_ih, W_hh, b_ih, b_hh, Wp, bp, pprobe);
    }
}

// Round 8
// 558.440 us; speedup vs baseline: 2.1092x; 2.1092x over previous
//
#include <hip/hip_runtime.h>
#include <math.h>

#define NB 512
#define NL 336
#define NC 321
#define NS 28
#define NW 12
#define NH 25
#define NP 8
#define NG 100
#define NT (NS + NP - 1)  // 35 cell steps
#define BSL 32            // batches per wave (2 MFMA column-tiles)

typedef __attribute__((ext_vector_type(8))) short bf16x8;
typedef __attribute__((ext_vector_type(4))) float f32x4;

union B8 { bf16x8 v; short s[8]; };
union BU { bf16x8 v; unsigned u[4]; };

// round-to-nearest bf16 (weights, built once)
__device__ __forceinline__ short brtn_s(float x) {
    union { float f; unsigned u; } c; c.f = x;
    return (short)((c.u + 0x8000u) >> 16);
}
__device__ __forceinline__ float fhi_f(float x) {
    union { float f; unsigned u; } c; c.f = x; c.u &= 0xFFFF0000u; return c.f;
}
__device__ __forceinline__ short bhi_s(float x) {
    union { float f; unsigned u; } c; c.f = x; return (short)(c.u >> 16);
}
// low16 = bf16(hi of a), high16 = bf16(hi of b)
__device__ __forceinline__ unsigned pack_hi2(float a, float b) {
    union { float f; unsigned u; } x, y; x.f = a; y.f = b;
    return (x.u >> 16) | (y.u & 0xFFFF0000u);
}

// q==3 lane carries the extra K-slots: k25=xt(hi/lo), k26=1@hi (A=bias_hi),
// k27=1@lo (A=bias_lo), k28=xt_hi@hi (A=wx_lo), k29..31=0.
__device__ __forceinline__ void set_q3(BU& h, BU& l, bool q3, float xt) {
    union { float f; unsigned u; } xu, xl;
    xu.f = xt; xl.f = xt - fhi_f(xt);
    h.u[0] = q3 ? ((h.u[0] & 0xFFFFu) | (xu.u & 0xFFFF0000u)) : h.u[0];
    l.u[0] = q3 ? ((l.u[0] & 0xFFFFu) | (xl.u & 0xFFFF0000u)) : l.u[0];
    h.u[1] = q3 ? 0x00003F80u : h.u[1];
    l.u[1] = q3 ? 0x3F800000u : l.u[1];
    h.u[2] = q3 ? (xu.u >> 16) : h.u[2];
    l.u[2] = q3 ? 0u : l.u[2];
    h.u[3] = q3 ? 0u : h.u[3];
    l.u[3] = q3 ? 0u : l.u[3];
}

// ---------------- Stage 1: mean + segment embedding (transposed out) --------
extern "C" __global__ __launch_bounds__(384)
void k_seg(const float* __restrict__ x, const float* __restrict__ seg,
           float* __restrict__ seg_inT, float* __restrict__ meanw) {
    const int b = blockIdx.x;
    const int c = threadIdx.x;
    if (c >= NC) return;
    float sw[NW];
#pragma unroll
    for (int w = 0; w < NW; ++w) sw[w] = seg[c * NW + w];
    float acc[NS];
    float sum = 0.0f;
    const float* xb = x + (size_t)b * NL * NC + c;
#pragma unroll 1
    for (int s = 0; s < NS; ++s) {
        float a = 0.0f;
#pragma unroll
        for (int w = 0; w < NW; ++w) {
            float v = xb[(s * NW + w) * NC];
            sum += v;
            a = fmaf(v, sw[w], a);
        }
        acc[s] = a;
    }
    const float mean = sum * (1.0f / (float)NL);
    float ssum = 0.0f;
#pragma unroll
    for (int w = 0; w < NW; ++w) ssum += sw[w];
    meanw[b * NC + c] = mean;
#pragma unroll
    for (int s = 0; s < NS; ++s)
        seg_inT[((size_t)s * NC + c) * NB + b] = acc[s] - mean * ssum;
}

// ---------------- Stage 2: MFMA LSTM, zero-LDS recurrence -------------------
// One wave per (channel, 32-batch slab), 1-wave blocks, all waves co-resident.
// Gate rows permuted j = q*8+mg (8 C-tiles, M=128, rows j>=25 zero): lane
// (bb,q) owns h[8q..8q+7] for batch bb == exactly its next-step B-fragment
// slots (k=8q..8q+7, col=bb). h stays in registers; LDS is not used at all.
extern "C" __global__ __launch_bounds__(64)
void k_lstm(const float* __restrict__ seg_inT, const float* __restrict__ W_ih,
            const float* __restrict__ W_hh, const float* __restrict__ b_ih,
            const float* __restrict__ b_hh, const float* __restrict__ Wp,
            const float* __restrict__ bp, float* __restrict__ preds) {
    const int c = blockIdx.x;
    const int b0 = blockIdx.y * BSL;
    const int lane = threadIdx.x;
    const int bb = lane & 15;         // column (batch) / A-row
    const int q  = lane >> 4;         // k-chunk / C row-quad
    const bool q3 = (q == 3);

    // ---- hoisted A-fragments from global (one-time, L2/L3-resident) ----
    // A lane: row=bb <-> (gate=bb&3, j=(bb>>2)*8+mg), k = q*8+e
    const int qq = bb >> 2, rr = bb & 3;
    const float* __restrict__ whh = W_hh + (size_t)c * NG * NH;
    const float* __restrict__ wxp = W_ih + (size_t)c * NG;
    const float* __restrict__ bip = b_ih + (size_t)c * NG;
    const float* __restrict__ bhp = b_hh + (size_t)c * NG;
    bf16x8 afr[8];
#pragma unroll 1
    for (int mg = 0; mg < 8; ++mg) {
        const int jj = qq * 8 + mg;
        const int grow = rr * NH + jj;
        B8 f0;
#pragma unroll
        for (int e = 0; e < 8; ++e) {
            const int k = q * 8 + e;
            short v0 = 0;
            if (jj < NH) {
                if (k < NH)         v0 = brtn_s(whh[grow * NH + k]);
                else if (k == 25)   v0 = brtn_s(wxp[grow]);
                else if (k == 26)   v0 = bhi_s(bip[grow] + bhp[grow]);
                else if (k == 27)   { const float bs = bip[grow] + bhp[grow];
                                      v0 = brtn_s(bs - fhi_f(bs)); }
                else if (k == 28)   { const float wx = wxp[grow];
                                      v0 = brtn_s(wx - fhi_f(wx)); }
            }
            f0.s[e] = v0;
        }
        afr[mg] = f0.v;
    }

    float wpl[8];
#pragma unroll
    for (int mg = 0; mg < 8; ++mg) {
        const int j = q * 8 + mg;
        wpl[mg] = (j < NH) ? Wp[(size_t)c * NH + j] : 0.0f;
    }
    const float bpc = bp[c];

    // ---- initial B-fragments: h = 0, xt = seg_in[s=0] ----
    BU ph[2], pl[2];
    {
        const float x0 = seg_inT[(size_t)c * NB + b0 + bb];
        const float x1 = seg_inT[(size_t)c * NB + b0 + 16 + bb];
#pragma unroll
        for (int nb = 0; nb < 2; ++nb) {
            ph[nb].u[0] = ph[nb].u[1] = ph[nb].u[2] = ph[nb].u[3] = 0u;
            pl[nb].u[0] = pl[nb].u[1] = pl[nb].u[2] = pl[nb].u[3] = 0u;
        }
        set_q3(ph[0], pl[0], q3, x0);
        set_q3(ph[1], pl[1], q3, x1);
    }

    float cst[2][8];
#pragma unroll
    for (int nb = 0; nb < 2; ++nb)
#pragma unroll
        for (int mg = 0; mg < 8; ++mg) cst[nb][mg] = 0.0f;

    // ---- recurrence: pure register dataflow, no LDS ----
#pragma unroll 1
    for (int t = 0; t < NT; ++t) {
        const bool enc_next = (t + 1 < NS);
        const bool do_proj = (t >= NS - 1);
        const bool have_next = (t + 1 < NT);

        // prefetch next encoder inputs early (L2/L3-resident)
        float xn0 = 0.0f, xn1 = 0.0f;
        if (enc_next) {
            const float* p = seg_inT + ((size_t)(t + 1) * NC + c) * NB + b0;
            xn0 = p[bb]; xn1 = p[16 + bb];
        }

        float hnv[2][8];
        float pp0 = 0.0f, pp1 = 0.0f;
#pragma unroll
        for (int nb = 0; nb < 2; ++nb) {
#pragma unroll
            for (int mg = 0; mg < 8; ++mg) {
                f32x4 acc = {0.0f, 0.0f, 0.0f, 0.0f};
                acc = __builtin_amdgcn_mfma_f32_16x16x32_bf16(afr[mg], ph[nb].v, acc, 0, 0, 0);
                acc = __builtin_amdgcn_mfma_f32_16x16x32_bf16(afr[mg], pl[nb].v, acc, 0, 0, 0);
                // regs: 0=i, 1=f, 2=g, 3=o of hidden j=8q+mg, batch col
                const float ef = __expf(-acc[1]);
                const float ei = __expf(-acc[0]);
                const float eg = __expf(-2.0f * acc[2]);
                const float eo = __expf(-acc[3]);
                const float pig = (1.0f + ei) * (1.0f + eg);
                const float fp1 = 1.0f + ef;
                const float cn = __fdividef(fmaf(cst[nb][mg], pig, (1.0f - eg) * fp1),
                                            fp1 * pig);
                const float et = __expf(-2.0f * cn);
                const float hn = __fdividef(1.0f - et, (1.0f + eo) * (1.0f + et));
                cst[nb][mg] = cn;
                hnv[nb][mg] = hn;
                if (do_proj) {
                    if (nb == 0) pp0 = fmaf(hn, wpl[mg], pp0);
                    else         pp1 = fmaf(hn, wpl[mg], pp1);
                }
            }
        }

        float ov0 = 0.0f, ov1 = 0.0f;
        if (do_proj) {
            pp0 += __shfl_xor(pp0, 16);
            pp0 += __shfl_xor(pp0, 32);
            pp1 += __shfl_xor(pp1, 16);
            pp1 += __shfl_xor(pp1, 32);
            ov0 = pp0 + bpc;
            ov1 = pp1 + bpc;
            if (q == 0) {
                float* pd = preds + ((size_t)c * NP + (t - (NS - 1))) * NB + b0;
                pd[bb] = ov0;
                pd[16 + bb] = ov1;
            }
        }

        if (have_next) {
            // repack h (hi/lo) into next step's B-fragments, in-register
#pragma unroll
            for (int nb = 0; nb < 2; ++nb) {
#pragma unroll
                for (int e = 0; e < 4; ++e) {
                    const float a = hnv[nb][2 * e], b = hnv[nb][2 * e + 1];
                    ph[nb].u[e] = pack_hi2(a, b);
                    pl[nb].u[e] = pack_hi2(a - fhi_f(a), b - fhi_f(b));
                }
            }
            const float xt0 = enc_next ? xn0 : ov0;
            const float xt1 = enc_next ? xn1 : ov1;
            set_q3(ph[0], pl[0], q3, xt0);
            set_q3(ph[1], pl[1], q3, xt1);
        }
    }
}

// ---------------- Stage 3: expand predictions to output ---------------------
extern "C" __global__ __launch_bounds__(384)
void k_out(const float* __restrict__ preds, const float* __restrict__ seg,
           const float* __restrict__ meanw, float* __restrict__ out) {
    const int b = blockIdx.x;
    const int c = threadIdx.x;
    if (c >= NC) return;
    float sw[NW];
#pragma unroll
    for (int w = 0; w < NW; ++w) sw[w] = seg[c * NW + w];
    const float mean = meanw[b * NC + c];
    float pv[NP];
#pragma unroll
    for (int p = 0; p < NP; ++p) pv[p] = preds[((size_t)c * NP + p) * NB + b];
    float* ob = out + (size_t)b * (NP * NW) * NC + c;
#pragma unroll
    for (int p = 0; p < NP; ++p) {
#pragma unroll
        for (int w = 0; w < NW; ++w) {
            ob[(p * NW + w) * NC] = fmaf(pv[p], sw[w], mean);
        }
    }
}

extern "C" void kernel_launch(void* const* d_in, const int* in_sizes, int n_in,
                              void* d_out, int out_size, void* d_ws, size_t ws_size,
                              hipStream_t stream) {
    const float* x    = (const float*)d_in[0];
    const float* seg  = (const float*)d_in[1];
    const float* W_ih = (const float*)d_in[2];
    const float* W_hh = (const float*)d_in[3];
    const float* b_ih = (const float*)d_in[4];
    const float* b_hh = (const float*)d_in[5];
    const float* Wp   = (const float*)d_in[6];
    const float* bp   = (const float*)d_in[7];
    float* out = (float*)d_out;

    float* seg_inT = (float*)d_ws;                     // 28*321*512
    float* meanw   = seg_inT + (size_t)NS * NC * NB;   // 512*321
    float* preds   = meanw + (size_t)NB * NC;          // 321*8*512

    k_seg<<<NB, 384, 0, stream>>>(x, seg, seg_inT, meanw);
    k_lstm<<<dim3(NC, NB / BSL), 64, 0, stream>>>(seg_inT, W_ih, W_hh, b_ih, b_hh, Wp, bp, preds);
    k_out<<<NB, 384, 0, stream>>>(preds, seg, meanw, out);
}

// Round 9
// 532.553 us; speedup vs baseline: 2.2117x; 1.0486x over previous
//
#include <hip/hip_runtime.h>
#include <math.h>

#define NB 512
#define NL 336
#define NC 321
#define NS 28
#define NW 12
#define NH 25
#define NP 8
#define NG 100
#define NT (NS + NP - 1)  // 35 cell steps
#define BSL 16            // batches per wave (1 MFMA column-tile)
#define WPB 4             // independent waves per 256-thread block

typedef __attribute__((ext_vector_type(8))) short bf16x8;
typedef __attribute__((ext_vector_type(4))) float f32x4;

union B8 { bf16x8 v; short s[8]; };
union BU { bf16x8 v; unsigned u[4]; };

// round-to-nearest bf16 (weights, built once)
__device__ __forceinline__ short brtn_s(float x) {
    union { float f; unsigned u; } c; c.f = x;
    return (short)((c.u + 0x8000u) >> 16);
}
__device__ __forceinline__ float fhi_f(float x) {
    union { float f; unsigned u; } c; c.f = x; c.u &= 0xFFFF0000u; return c.f;
}
__device__ __forceinline__ short bhi_s(float x) {
    union { float f; unsigned u; } c; c.f = x; return (short)(c.u >> 16);
}
// low16 = bf16(hi of a), high16 = bf16(hi of b)
__device__ __forceinline__ unsigned pack_hi2(float a, float b) {
    union { float f; unsigned u; } x, y; x.f = a; y.f = b;
    return (x.u >> 16) | (y.u & 0xFFFF0000u);
}

// q==3 lane carries the extra K-slots: k25=xt(hi/lo), k26=1@hi (A=bias_hi),
// k27=1@lo (A=bias_lo), k28=xt_hi@hi (A=wx_lo), k29..31=0.
__device__ __forceinline__ void set_q3(BU& h, BU& l, bool q3, float xt) {
    union { float f; unsigned u; } xu, xl;
    xu.f = xt; xl.f = xt - fhi_f(xt);
    h.u[0] = q3 ? ((h.u[0] & 0xFFFFu) | (xu.u & 0xFFFF0000u)) : h.u[0];
    l.u[0] = q3 ? ((l.u[0] & 0xFFFFu) | (xl.u & 0xFFFF0000u)) : l.u[0];
    h.u[1] = q3 ? 0x00003F80u : h.u[1];
    l.u[1] = q3 ? 0x3F800000u : l.u[1];
    h.u[2] = q3 ? (xu.u >> 16) : h.u[2];
    l.u[2] = q3 ? 0u : l.u[2];
    h.u[3] = q3 ? 0u : h.u[3];
    l.u[3] = q3 ? 0u : l.u[3];
}

// ---------------- Stage 1: mean + segment embedding (transposed out) --------
extern "C" __global__ __launch_bounds__(384)
void k_seg(const float* __restrict__ x, const float* __restrict__ seg,
           float* __restrict__ seg_inT, float* __restrict__ meanw) {
    const int b = blockIdx.x;
    const int c = threadIdx.x;
    if (c >= NC) return;
    float sw[NW];
#pragma unroll
    for (int w = 0; w < NW; ++w) sw[w] = seg[c * NW + w];
    float acc[NS];
    float sum = 0.0f;
    const float* xb = x + (size_t)b * NL * NC + c;
#pragma unroll 1
    for (int s = 0; s < NS; ++s) {
        float a = 0.0f;
#pragma unroll
        for (int w = 0; w < NW; ++w) {
            float v = xb[(s * NW + w) * NC];
            sum += v;
            a = fmaf(v, sw[w], a);
        }
        acc[s] = a;
    }
    const float mean = sum * (1.0f / (float)NL);
    float ssum = 0.0f;
#pragma unroll
    for (int w = 0; w < NW; ++w) ssum += sw[w];
    meanw[b * NC + c] = mean;
#pragma unroll
    for (int s = 0; s < NS; ++s)
        seg_inT[((size_t)s * NC + c) * NB + b] = acc[s] - mean * ssum;
}

// ---------------- Stage 2: MFMA LSTM, zero-LDS recurrence -------------------
// 4 independent waves per 256-thread block (no barriers, no LDS at all); each
// wave owns (channel, 16-batch tile). Gate rows permuted j=q*8+mg: lane (bb,q)
// owns h[8q..8q+7] of batch bb == exactly its next-step B-fragment slots
// (k=8q..8q+7, col=bb) -> recurrence is pure register dataflow.
extern "C" __global__ __launch_bounds__(256, 4)
void k_lstm(const float* __restrict__ seg_inT, const float* __restrict__ W_ih,
            const float* __restrict__ W_hh, const float* __restrict__ b_ih,
            const float* __restrict__ b_hh, const float* __restrict__ Wp,
            const float* __restrict__ bp, float* __restrict__ preds) {
    const int c = blockIdx.x;
    const int wv = threadIdx.x >> 6;
    const int lane = threadIdx.x & 63;
    const int b0 = (blockIdx.y * WPB + wv) * BSL;
    const int bb = lane & 15;         // column (batch) / A-row
    const int q  = lane >> 4;         // k-chunk / C row-quad
    const bool q3 = (q == 3);

    // ---- hoisted A-fragments from global (one-time, L2/L3-resident) ----
    // A lane: row=bb <-> (gate=bb&3, j=(bb>>2)*8+mg), k = q*8+e
    const int qq = bb >> 2, rr = bb & 3;
    const float* __restrict__ whh = W_hh + (size_t)c * NG * NH;
    const float* __restrict__ wxp = W_ih + (size_t)c * NG;
    const float* __restrict__ bip = b_ih + (size_t)c * NG;
    const float* __restrict__ bhp = b_hh + (size_t)c * NG;
    bf16x8 afr[8];
#pragma unroll 1
    for (int mg = 0; mg < 8; ++mg) {
        const int jj = qq * 8 + mg;
        const int grow = rr * NH + jj;
        B8 f0;
#pragma unroll
        for (int e = 0; e < 8; ++e) {
            const int k = q * 8 + e;
            short v0 = 0;
            if (jj < NH) {
                if (k < NH)         v0 = brtn_s(whh[grow * NH + k]);
                else if (k == 25)   v0 = brtn_s(wxp[grow]);
                else if (k == 26)   v0 = bhi_s(bip[grow] + bhp[grow]);
                else if (k == 27)   { const float bs = bip[grow] + bhp[grow];
                                      v0 = brtn_s(bs - fhi_f(bs)); }
                else if (k == 28)   { const float wx = wxp[grow];
                                      v0 = brtn_s(wx - fhi_f(wx)); }
            }
            f0.s[e] = v0;
        }
        afr[mg] = f0.v;
    }

    float wpl[8];
#pragma unroll
    for (int mg = 0; mg < 8; ++mg) {
        const int j = q * 8 + mg;
        wpl[mg] = (j < NH) ? Wp[(size_t)c * NH + j] : 0.0f;
    }
    const float bpc = bp[c];

    // ---- initial B-fragments: h = 0, xt = seg_in[s=0] ----
    BU ph, pl;
    {
        const float x0 = seg_inT[(size_t)c * NB + b0 + bb];
        ph.u[0] = ph.u[1] = ph.u[2] = ph.u[3] = 0u;
        pl.u[0] = pl.u[1] = pl.u[2] = pl.u[3] = 0u;
        set_q3(ph, pl, q3, x0);
    }

    float cst[8];
#pragma unroll
    for (int mg = 0; mg < 8; ++mg) cst[mg] = 0.0f;

    // ---- recurrence: pure register dataflow ----
#pragma unroll 1
    for (int t = 0; t < NT; ++t) {
        const bool enc_next = (t + 1 < NS);
        const bool do_proj = (t >= NS - 1);
        const bool have_next = (t + 1 < NT);

        // prefetch next encoder input early (L2/L3-resident)
        float xn = 0.0f;
        if (enc_next)
            xn = seg_inT[((size_t)(t + 1) * NC + c) * NB + b0 + bb];

        float hnv[8];
        float pp = 0.0f;
#pragma unroll
        for (int mg = 0; mg < 8; ++mg) {
            f32x4 acc = {0.0f, 0.0f, 0.0f, 0.0f};
            acc = __builtin_amdgcn_mfma_f32_16x16x32_bf16(afr[mg], ph.v, acc, 0, 0, 0);
            acc = __builtin_amdgcn_mfma_f32_16x16x32_bf16(afr[mg], pl.v, acc, 0, 0, 0);
            // regs: 0=i, 1=f, 2=g, 3=o of hidden j=8q+mg, batch bb
            const float ef = __expf(-acc[1]);
            const float ei = __expf(-acc[0]);
            const float eg = __expf(-2.0f * acc[2]);
            const float eo = __expf(-acc[3]);
            const float pig = (1.0f + ei) * (1.0f + eg);
            const float fp1 = 1.0f + ef;
            const float cn = __fdividef(fmaf(cst[mg], pig, (1.0f - eg) * fp1),
                                        fp1 * pig);
            const float et = __expf(-2.0f * cn);
            const float hn = __fdividef(1.0f - et, (1.0f + eo) * (1.0f + et));
            cst[mg] = cn;
            hnv[mg] = hn;
            if (do_proj) pp = fmaf(hn, wpl[mg], pp);
        }

        float ov = 0.0f;
        if (do_proj) {
            pp += __shfl_xor(pp, 16);
            pp += __shfl_xor(pp, 32);
            ov = pp + bpc;
            if (q == 0)
                preds[((size_t)c * NP + (t - (NS - 1))) * NB + b0 + bb] = ov;
        }

        if (have_next) {
            // repack h (hi/lo) into next step's B-fragment, in-register
#pragma unroll
            for (int e = 0; e < 4; ++e) {
                const float a = hnv[2 * e], b = hnv[2 * e + 1];
                ph.u[e] = pack_hi2(a, b);
                pl.u[e] = pack_hi2(a - fhi_f(a), b - fhi_f(b));
            }
            set_q3(ph, pl, q3, enc_next ? xn : ov);
        }
    }
}

// ---------------- Stage 3: expand predictions to output ---------------------
extern "C" __global__ __launch_bounds__(384)
void k_out(const float* __restrict__ preds, const float* __restrict__ seg,
           const float* __restrict__ meanw, float* __restrict__ out) {
    const int b = blockIdx.x;
    const int c = threadIdx.x;
    if (c >= NC) return;
    float sw[NW];
#pragma unroll
    for (int w = 0; w < NW; ++w) sw[w] = seg[c * NW + w];
    const float mean = meanw[b * NC + c];
    float pv[NP];
#pragma unroll
    for (int p = 0; p < NP; ++p) pv[p] = preds[((size_t)c * NP + p) * NB + b];
    float* ob = out + (size_t)b * (NP * NW) * NC + c;
#pragma unroll
    for (int p = 0; p < NP; ++p) {
#pragma unroll
        for (int w = 0; w < NW; ++w) {
            ob[(p * NW + w) * NC] = fmaf(pv[p], sw[w], mean);
        }
    }
}

extern "C" void kernel_launch(void* const* d_in, const int* in_sizes, int n_in,
                              void* d_out, int out_size, void* d_ws, size_t ws_size,
                              hipStream_t stream) {
    const float* x    = (const float*)d_in[0];
    const float* seg  = (const float*)d_in[1];
    const float* W_ih = (const float*)d_in[2];
    const float* W_hh = (const float*)d_in[3];
    const float* b_ih = (const float*)d_in[4];
    const float* b_hh = (const float*)d_in[5];
    const float* Wp   = (const float*)d_in[6];
    const float* bp   = (const float*)d_in[7];
    float* out = (float*)d_out;

    float* seg_inT = (float*)d_ws;                     // 28*321*512
    float* meanw   = seg_inT + (size_t)NS * NC * NB;   // 512*321
    float* preds   = meanw + (size_t)NB * NC;          // 321*8*512

    k_seg<<<NB, 384, 0, stream>>>(x, seg, seg_inT, meanw);
    k_lstm<<<dim3(NC, NB / (BSL * WPB)), 256, 0, stream>>>(
        seg_inT, W_ih, W_hh, b_ih, b_hh, Wp, bp, preds);
    k_out<<<NB, 384, 0, stream>>>(preds, seg, meanw, out);
}